// Round 20
// baseline (143.075 us; speedup 1.0000x reference)
//
#include <hip/hip_runtime.h>
#include <hip/hip_bf16.h>

#define T_ 8
#define N0_ 32
#define N1_ 32
#define SP_ (N0_*N1_)   /* 1024 spatial cells */
#define S_ (T_*SP_)     /* 8192 space-time cells */
#define E_ 256
#define P_ 16
#define NH_ 8
#define HD_ 32

typedef __attribute__((ext_vector_type(8))) short short8;
typedef __attribute__((ext_vector_type(4))) float f32x4;
typedef __attribute__((ext_vector_type(8))) unsigned short u16x8;

__device__ __forceinline__ unsigned short f2bf(float f) {
  __hip_bfloat16 h = __float2bfloat16(f);
  return *reinterpret_cast<unsigned short*>(&h);
}
__device__ __forceinline__ float bf2f(unsigned short u) {
  return __uint_as_float((unsigned)u << 16);
}

// async global->LDS, 16B per lane; dst = wave-uniform base + lane*16
__device__ __forceinline__ void gl_lds16(const void* g, void* l) {
  __builtin_amdgcn_global_load_lds(
      (const __attribute__((address_space(1))) unsigned int*)(g),
      (__attribute__((address_space(3))) unsigned int*)(l), 16, 0, 0);
}

// ============ prep: [0..256) stats+xgrid+assign | [256..320) wtrans ========================
__global__ __launch_bounds__(256) void prep(const float* __restrict__ x,
                                            const float* __restrict__ tg,
                                            const float* __restrict__ grid,
                                            float* __restrict__ out,
                                            int* __restrict__ counts,
                                            int* __restrict__ cell_raw,
                                            const float* __restrict__ Wq,
                                            const float* __restrict__ Wk,
                                            const float* __restrict__ Wv,
                                            const float* __restrict__ Wo,
                                            unsigned short* __restrict__ wT,
                                            int m, int n, int tot_xg) {
  __shared__ float ts[64][65];
  __shared__ float st[4][6];
  int bid = blockIdx.x;
  int tid = threadIdx.x;
  if (bid < 256) {
    // ---- stats (byte-identical fp32 op order) + x_grid + assign ----
    if (tid < 64) {
      float mn0 = 1e30f, mx0 = -1e30f, mn1 = 1e30f, mx1 = -1e30f;
      for (int i = tid; i < SP_; i += 64) {
        float g0 = grid[i*2], g1 = grid[i*2+1];
        mn0 = fminf(mn0, g0); mx0 = fmaxf(mx0, g0);
        mn1 = fminf(mn1, g1); mx1 = fmaxf(mx1, g1);
      }
      for (int msk = 32; msk; msk >>= 1) {
        mn0 = fminf(mn0, __shfl_xor(mn0, msk));
        mx0 = fmaxf(mx0, __shfl_xor(mx0, msk));
        mn1 = fminf(mn1, __shfl_xor(mn1, msk));
        mx1 = fmaxf(mx1, __shfl_xor(mx1, msk));
      }
      if (tid == 0) {
        for (int b = 0; b < m; ++b) {
          float tmn = 1e30f, tmx = -1e30f;
          for (int tt = 0; tt < T_; ++tt) {
            float v = tg[b*T_ + tt];
            tmn = fminf(tmn, v); tmx = fmaxf(tmx, v);
          }
          st[b][0] = tmn; st[b][1] = mn0; st[b][2] = mn1;
          st[b][3] = (tmx - tmn) / (float)(T_ - 1);
          st[b][4] = (mx0 - mn0) / (float)(N0_ - 1);
          st[b][5] = (mx1 - mn1) / (float)(N1_ - 1);
        }
      }
    }
    __syncthreads();
    int idx = bid * 256 + tid;
    if (idx < tot_xg) {                       // x_grid
      int sp = idx & (SP_ - 1);
      int bt = idx >> 10;
      out[idx*3 + 0] = tg[bt];
      out[idx*3 + 1] = grid[sp*2 + 0];
      out[idx*3 + 2] = grid[sp*2 + 1];
    }
    if (idx < m*n) {                          // assign
      int b = idx / n;
      int j = idx - b*n;
      const float* s = st[b];
      float xt = x[(size_t)idx*3 + 0], x0 = x[(size_t)idx*3 + 1], x1 = x[(size_t)idx*3 + 2];
      float m0 = floorf((xt - s[0] + s[3]*0.5f) / s[3]);
      float m1 = floorf((x0 - s[1] + s[4]*0.5f) / s[4]);
      float m2 = floorf((x1 - s[2] + s[5]*0.5f) / s[5]);
      m0 = fminf(fmaxf(m0, 0.f), (float)(T_ - 1));
      m1 = fminf(fmaxf(m1, 0.f), (float)(N0_ - 1));
      m2 = fminf(fmaxf(m2, 0.f), (float)(N1_ - 1));
      int sc = (int)m0 * SP_ + (int)m1 * N1_ + (int)m2;
      int cg = b * S_ + sc;
      int old = atomicAdd(&counts[cg], 1);
      if (old < P_) cell_raw[(size_t)cg * P_ + old] = j;
    }
    return;
  }
  // ---- weight transpose+convert: wT[1024][256] = [Wq|Wk|Wv|Wo]^T ----
  int wb = bid - 256;
  int mat = wb >> 4;
  int tile = wb & 15;
  int tr = (tile >> 2) * 64;
  int tc = (tile & 3) * 64;
  const float* W = mat == 0 ? Wq : mat == 1 ? Wk : mat == 2 ? Wv : Wo;
  int r = tid >> 2, c0 = (tid & 3) * 16;
#pragma unroll
  for (int i = 0; i < 4; ++i) {
    float4 v = *(const float4*)&W[(size_t)(tr + r) * 256 + tc + c0 + i*4];
    ts[r][c0 + i*4 + 0] = v.x; ts[r][c0 + i*4 + 1] = v.y;
    ts[r][c0 + i*4 + 2] = v.z; ts[r][c0 + i*4 + 3] = v.w;
  }
  __syncthreads();
  u16x8 o0, o1;
#pragma unroll
  for (int i = 0; i < 8; ++i) o0[i] = f2bf(ts[c0 + i][r]);
#pragma unroll
  for (int i = 0; i < 8; ++i) o1[i] = f2bf(ts[c0 + 8 + i][r]);
  unsigned short* dst = wT + (size_t)(mat * 256 + tc + r) * 256 + tr + c0;
  *(u16x8*)dst = o0;
  *(u16x8*)(dst + 8) = o1;
}

// ============ fp32-A g2l GEMM body: 256 thr / 4 waves, single-buffered 48KB (R19) ==========
template <typename OutT>
__device__ __forceinline__ void f32a_body(char* __restrict__ ldsbuf,
                                          const float* __restrict__ A,
                                          const unsigned short* __restrict__ BT,
                                          OutT* __restrict__ C,
                                          int CP, int ldc, int L, int tid) {
  float* As = (float*)ldsbuf;                              // [128][64] fp32, row = 256B
  unsigned short* Bs = (unsigned short*)(ldsbuf + 32768);  // [128][64] bf16, row = 128B
  int rp = L / CP, cp = L - rp * CP;

  int wid = tid >> 6, lane = tid & 63, l15 = lane & 15, slot = lane >> 4;
  int wr = (wid >> 1) * 64, wc = (wid & 1) * 64;   // wave tile 64x64

  int arl = lane >> 4, aG = lane & 15;             // A-DMA: 4 rows x 16 granules
  int brl = lane >> 3, bG = lane & 7;              // B-DMA: 8 rows x 8 granules

  f32x4 acc[4][4] = {};

#pragma unroll
  for (int kt = 0; kt < 4; ++kt) {
#pragma unroll
    for (int d = 0; d < 8; ++d) {                  // A: 8 DMAs/wave (4 rows each)
      int row = wid * 32 + d * 4 + arl;
      const float* src = A + (size_t)(rp * 128 + row) * 256 + kt * 64
                         + (size_t)((aG ^ (row & 15)) << 2);
      gl_lds16(src, As + (wid * 32 + d * 4) * 64);
    }
#pragma unroll
    for (int d = 0; d < 4; ++d) {                  // B: 4 DMAs/wave (8 rows each)
      int row = wid * 32 + d * 8 + brl;
      const unsigned short* src = BT + (size_t)(cp * 128 + row) * 256 + kt * 64
                                  + (size_t)((bG ^ (row & 7)) << 3);
      gl_lds16(src, Bs + (wid * 32 + d * 8) * 64);
    }
    asm volatile("s_waitcnt vmcnt(0)" ::: "memory");
    __builtin_amdgcn_s_barrier();
    asm volatile("" ::: "memory");
#pragma unroll
    for (int kf = 0; kf < 2; ++kf) {
      short8 afr[4], bfr[4];
      int kg = kf * 4 + slot;
#pragma unroll
      for (int mm = 0; mm < 4; ++mm) {
        int row = wr + mm * 16 + l15;              // row & 15 == l15
        f32x4 a0 = *(const f32x4*)&As[row * 64 + (((2 * kg    ) ^ l15) << 2)];
        f32x4 a1 = *(const f32x4*)&As[row * 64 + (((2 * kg + 1) ^ l15) << 2)];
        short8 af;
        af[0]=f2bf(a0[0]); af[1]=f2bf(a0[1]); af[2]=f2bf(a0[2]); af[3]=f2bf(a0[3]);
        af[4]=f2bf(a1[0]); af[5]=f2bf(a1[1]); af[6]=f2bf(a1[2]); af[7]=f2bf(a1[3]);
        afr[mm] = af;
      }
#pragma unroll
      for (int nn = 0; nn < 4; ++nn) {
        int col = wc + nn * 16 + l15;              // col & 7 == l15 & 7
        bfr[nn] = *(const short8*)&Bs[col * 64 + ((kg ^ (l15 & 7)) << 3)];
      }
#pragma unroll
      for (int mm = 0; mm < 4; ++mm)
#pragma unroll
        for (int nn = 0; nn < 4; ++nn)
          acc[mm][nn] = __builtin_amdgcn_mfma_f32_16x16x32_bf16(afr[mm], bfr[nn], acc[mm][nn], 0, 0, 0);
    }
    asm volatile("" ::: "memory");
    __builtin_amdgcn_s_barrier();   // all waves done reading before next-kt overwrite
    asm volatile("" ::: "memory");
  }

  // ---- epilogue: C/D layout col=lane&15, row=(lane>>4)*4+j ----
#pragma unroll
  for (int mm = 0; mm < 4; ++mm) {
#pragma unroll
    for (int nn = 0; nn < 4; ++nn) {
      int grow0 = rp * 128 + wr + mm * 16 + slot * 4;
      int gcol  = cp * 128 + wc + nn * 16 + l15;
#pragma unroll
      for (int j = 0; j < 4; ++j) {
        size_t o = (size_t)(grow0 + j) * ldc + gcol;
        if constexpr (__is_same(OutT, float)) C[o] = acc[mm][nn][j];
        else                                  C[o] = __float2bfloat16(acc[mm][nn][j]);
      }
    }
  }
}

// ============ phase2: [0..1024) k16 GEMM | [1024..1072) lat GEMM | [1072..1200) finalize ===
__global__ __launch_bounds__(256, 3) void phase2(const float* __restrict__ z,
                                                 const unsigned short* __restrict__ wT,
                                                 __hip_bfloat16* __restrict__ k16,
                                                 const float* __restrict__ latents,
                                                 float* __restrict__ lat,
                                                 const int* __restrict__ counts,
                                                 int* __restrict__ cell_raw,
                                                 int* __restrict__ pts2, int total) {
  __shared__ char lds[49152];   // 48KB: A fp32 32KB + B bf16 16KB, shared by both paths
  int bid = blockIdx.x;
  if (bid < 1024) {
    int L = (bid & 7) * 128 + (bid >> 3);     // XCD-chunked over the k16 range
    f32a_body<__hip_bfloat16>(lds, z, wT + (size_t)256*256, k16, 2, 256, L, threadIdx.x);
    return;
  }
  if (bid < 1072) {
    f32a_body<float>(lds, latents, wT, lat, 6, 768, bid - 1024, threadIdx.x);
    return;
  }
  int cg = (bid - 1072) * 256 + threadIdx.x;
  if (cg >= total) return;
  int cnt = counts[cg];
  int stored = cnt < P_ ? cnt : P_;
  int eff = cnt < (P_ - 1) ? cnt : (P_ - 1);
  int* p = cell_raw + (size_t)cg * P_;
  for (int i = 1; i < stored; ++i) {   // insertion sort ascending (original index order)
    int key = p[i]; int j = i - 1;
    while (j >= 0 && p[j] > key) { p[j+1] = p[j]; --j; }
    p[j+1] = key;
  }
  int* o = pts2 + (size_t)cg * P_;
  o[0] = eff;
  for (int i = 0; i < eff; ++i) o[1 + i] = p[i];
}

// ============ mega_attn: k-logits + z-mix + in-block Wv and Wo projections =================
// Block = 16 cells, 256 thr / 4 waves (wave owns 4 cells). Logits: k16 rows + 3-shfl group
// reduce (as proven attn); per-head e broadcast = 8 shfl/point. Mix (8 heads x 4 dims) in
// regs -> swizzled mixlds bf16 -> MFMA vs Wv^T -> avlds -> MFMA vs Wo^T -> z_grid fp32.
__global__ __launch_bounds__(256, 2) void mega_attn(const float* __restrict__ z,
                                                    const float* __restrict__ latents,
                                                    const float* __restrict__ lat,
                                                    const __hip_bfloat16* __restrict__ k16,
                                                    const unsigned short* __restrict__ wTv,
                                                    const unsigned short* __restrict__ wTo,
                                                    const int* __restrict__ pts2,
                                                    float* __restrict__ outZ, int n) {
  __shared__ unsigned short mixlds[16 * 2048];   // 64KB: [cell][head*256+dim] swizzled
  __shared__ unsigned short avlds[16 * 256];     // 8KB:  [cell][attnV dim] swizzled
  const float scale = 0.17677669529663687f;  // 1/sqrt(32)
  int tid = threadIdx.x, w = tid >> 6, lane = tid & 63;
  int d0 = lane << 2;
  int l7 = lane & 7;
  int cg0 = blockIdx.x * 16;

  for (int cc = 0; cc < 4; ++cc) {
    int cellL = w * 4 + cc;
    int cellg = cg0 + cellL;
    int bidx = cellg >> 13;
    int c = cellg & (SP_ - 1);

    const float* latc = lat + c * 768 + d0;
    float4 q  = *(const float4*)latc;
    float4 kl = *(const float4*)(latc + 256);

    const int* pp = pts2 + (size_t)cellg * P_;
    int4 h0 = *(const int4*)pp;
    int eff = h0.x;

    float ss[8];
    float mx[8][4];
    // grid token: k from lat, z-row = latents[c]
    {
      float p = q.x*kl.x + q.y*kl.y + q.z*kl.z + q.w*kl.w;
      p += __shfl_xor(p, 1); p += __shfl_xor(p, 2); p += __shfl_xor(p, 4);
      float e = __expf(p * scale);
      float4 zl = *(const float4*)(latents + (size_t)c * 256 + d0);
#pragma unroll
      for (int h = 0; h < 8; ++h) {
        float eh = __shfl(e, (h << 3) | l7);
        ss[h] = eh;
        mx[h][0] = eh*zl.x; mx[h][1] = eh*zl.y; mx[h][2] = eh*zl.z; mx[h][3] = eh*zl.w;
      }
    }
    size_t bb = (size_t)bidx * n;
    const unsigned short* kp = (const unsigned short*)k16;
    int pt[4]; pt[0] = h0.y; pt[1] = h0.z; pt[2] = h0.w; pt[3] = 0;
    int done = 0, cap = 3;
    while (done < eff) {
      int np = eff - done; if (np > cap) np = cap;
      ushort4 kr[4]; float4 zr[4];
#pragma unroll
      for (int i = 0; i < 4; ++i) if (i < np) {
        size_t row = bb + (size_t)pt[i];
        kr[i] = *(const ushort4*)(kp + row * 256 + d0);
        zr[i] = *(const float4*)(z + row * 256 + d0);
      }
#pragma unroll
      for (int i = 0; i < 4; ++i) if (i < np) {
        float p = q.x*bf2f(kr[i].x) + q.y*bf2f(kr[i].y) + q.z*bf2f(kr[i].z) + q.w*bf2f(kr[i].w);
        p += __shfl_xor(p, 1); p += __shfl_xor(p, 2); p += __shfl_xor(p, 4);
        float e = __expf(p * scale);
#pragma unroll
        for (int h = 0; h < 8; ++h) {
          float eh = __shfl(e, (h << 3) | l7);
          ss[h] += eh;
          mx[h][0] += eh*zr[i].x; mx[h][1] += eh*zr[i].y;
          mx[h][2] += eh*zr[i].z; mx[h][3] += eh*zr[i].w;
        }
      }
      done += np;
      cap = 4;
      if (done < eff) {
        int4 hh = *(const int4*)(pp + 1 + done);   // done in {3,7,11} -> aligned
        pt[0] = hh.x; pt[1] = hh.y; pt[2] = hh.z; pt[3] = hh.w;
      }
    }
    // normalized mix -> mixlds bf16 (granule-XOR swizzle ^ cell&7)
    unsigned base = (unsigned)cellL * 4096;
    unsigned K = cellL & 7;
#pragma unroll
    for (int h = 0; h < 8; ++h) {
      float inv = 1.f / ss[h];
      unsigned g = (unsigned)(h * 32 + (lane >> 1));
      unsigned addr = base + ((g ^ K) << 4) + ((unsigned)(d0 & 7) << 1);
      ushort4 v;
      v.x = f2bf(mx[h][0] * inv); v.y = f2bf(mx[h][1] * inv);
      v.z = f2bf(mx[h][2] * inv); v.w = f2bf(mx[h][3] * inv);
      *(ushort4*)((char*)mixlds + addr) = v;
    }
  }
  __syncthreads();

  int l15 = lane & 15, slot = lane >> 4;
  // ---- proj1: attnV[16,256] = mix @ blockdiag(Wv); wave w covers heads {w, w+4} ----
#pragma unroll
  for (int hh = 0; hh < 2; ++hh) {
    int h = w + hh * 4;
    f32x4 acc0 = {}, acc1 = {};
#pragma unroll
    for (int ks = 0; ks < 8; ++ks) {
      unsigned gA = (unsigned)(h * 32 + ks * 4 + slot);
      short8 afr = *(const short8*)((const char*)mixlds + l15 * 4096 + ((gA ^ (unsigned)(l15 & 7)) << 4));
      short8 b0 = *(const short8*)(wTv + (size_t)(h * 32 + l15) * 256 + ks * 32 + slot * 8);
      short8 b1 = *(const short8*)(wTv + (size_t)(h * 32 + 16 + l15) * 256 + ks * 32 + slot * 8);
      acc0 = __builtin_amdgcn_mfma_f32_16x16x32_bf16(afr, b0, acc0, 0, 0, 0);
      acc1 = __builtin_amdgcn_mfma_f32_16x16x32_bf16(afr, b1, acc1, 0, 0, 0);
    }
#pragma unroll
    for (int j = 0; j < 4; ++j) {
      unsigned row = (unsigned)(slot * 4 + j);
      unsigned c0 = (unsigned)(h * 32 + l15);
      unsigned c1 = (unsigned)(h * 32 + 16 + l15);
      *(unsigned short*)((char*)avlds + row * 512 + (((c0 >> 3) ^ row) << 4) + ((c0 & 7) << 1)) = f2bf(acc0[j]);
      *(unsigned short*)((char*)avlds + row * 512 + (((c1 >> 3) ^ row) << 4) + ((c1 & 7) << 1)) = f2bf(acc1[j]);
    }
  }
  __syncthreads();

  // ---- proj2: out[16,256] = attnV @ Wo; wave w covers out cols w*64..w*64+63 ----
  f32x4 oacc[4] = {};
#pragma unroll
  for (int ks = 0; ks < 8; ++ks) {
    unsigned gA = (unsigned)(ks * 4 + slot);
    short8 afr = *(const short8*)((const char*)avlds + l15 * 512 + ((gA ^ (unsigned)l15) << 4));
#pragma unroll
    for (int nn = 0; nn < 4; ++nn) {
      short8 bf = *(const short8*)(wTo + (size_t)(w * 64 + nn * 16 + l15) * 256 + ks * 32 + slot * 8);
      oacc[nn] = __builtin_amdgcn_mfma_f32_16x16x32_bf16(afr, bf, oacc[nn], 0, 0, 0);
    }
  }
#pragma unroll
  for (int nn = 0; nn < 4; ++nn)
#pragma unroll
    for (int j = 0; j < 4; ++j)
      outZ[(size_t)(cg0 + slot * 4 + j) * 256 + w * 64 + nn * 16 + l15] = oacc[nn][j];
}

// -------------------------------------------------------------------------------------------
extern "C" void kernel_launch(void* const* d_in, const int* in_sizes, int n_in,
                              void* d_out, int out_size, void* d_ws, size_t ws_size,
                              hipStream_t stream) {
  const float* x       = (const float*)d_in[0];
  const float* z       = (const float*)d_in[1];
  const float* tg      = (const float*)d_in[2];
  const float* latents = (const float*)d_in[3];
  const float* grid    = (const float*)d_in[4];
  const float* Wq      = (const float*)d_in[5];
  const float* Wk      = (const float*)d_in[6];
  const float* Wv      = (const float*)d_in[7];
  const float* Wo      = (const float*)d_in[8];

  int m = in_sizes[2] / T_;              // 4
  int n = in_sizes[1] / (m * E_);        // 16384
  int MS = m * S_;                       // 32768
  float* out = (float*)d_out;
  int tot_xg = m * T_ * SP_;             // 32768 grid sites

  // ---- workspace carve (256B aligned) ----
  char* w = (char*)d_ws;
  auto alloc = [&](size_t bytes) { char* p = w; w += (bytes + 255) & ~(size_t)255; return p; };
  int*   counts     = (int*)  alloc((size_t)MS * 4);
  int*   cell_raw   = (int*)  alloc((size_t)MS * P_ * 4);
  int*   pts2       = (int*)  alloc((size_t)MS * P_ * 4);
  unsigned short* wT = (unsigned short*)alloc((size_t)1024 * 256 * 2);
  float* lat        = (float*)alloc((size_t)SP_ * 768 * 4);
  __hip_bfloat16* k16 = (__hip_bfloat16*)alloc((size_t)m * n * 256 * 2);

  // 0) zero the atomic counters
  (void)hipMemsetAsync(counts, 0, (size_t)MS * 4, stream);

  // 1) prep: stats+x_grid+assign | wtrans   (320 blocks)
  prep<<<320, 256, 0, stream>>>(x, tg, grid, out, counts, cell_raw,
                                Wq, Wk, Wv, Wo, wT, m, n, tot_xg);

  // 2) phase2: k16 GEMM fp32-A (1024) | lat GEMM fp32-A (48) | finalize (128)
  phase2<<<1200, 256, 0, stream>>>(z, wT, k16, latents, lat, counts, cell_raw, pts2, MS);

  // 3) mega attention: k-logits + z-mix + Wv/Wo in-block projections -> z_grid
  mega_attn<<<MS/16, 256, 0, stream>>>(z, latents, lat, k16,
                                       wT + (size_t)2*256*256, wT + (size_t)3*256*256,
                                       pts2, out + (size_t)tot_xg * 3, n);
}

// Round 21
// 83.357 us; speedup vs baseline: 1.7164x; 1.7164x over previous
//
#include <hip/hip_runtime.h>
#include <hip/hip_bf16.h>

#define T_ 8
#define N0_ 32
#define N1_ 32
#define SP_ (N0_*N1_)   /* 1024 spatial cells */
#define S_ (T_*SP_)     /* 8192 space-time cells */
#define E_ 256
#define P_ 16
#define NH_ 8
#define HD_ 32

typedef __attribute__((ext_vector_type(8))) short short8;
typedef __attribute__((ext_vector_type(4))) float f32x4;
typedef __attribute__((ext_vector_type(8))) unsigned short u16x8;

__device__ __forceinline__ unsigned short f2bf(float f) {
  __hip_bfloat16 h = __float2bfloat16(f);
  return *reinterpret_cast<unsigned short*>(&h);
}
__device__ __forceinline__ float bf2f(unsigned short u) {
  return __uint_as_float((unsigned)u << 16);
}

// async global->LDS, 16B per lane; dst = wave-uniform base + lane*16
__device__ __forceinline__ void gl_lds16(const void* g, void* l) {
  __builtin_amdgcn_global_load_lds(
      (const __attribute__((address_space(1))) unsigned int*)(g),
      (__attribute__((address_space(3))) unsigned int*)(l), 16, 0, 0);
}

// ============ prep: [0..256) stats+xgrid+assign | [256..320) wtrans ========================
__global__ __launch_bounds__(256) void prep(const float* __restrict__ x,
                                            const float* __restrict__ tg,
                                            const float* __restrict__ grid,
                                            float* __restrict__ out,
                                            int* __restrict__ counts,
                                            int* __restrict__ cell_raw,
                                            const float* __restrict__ Wq,
                                            const float* __restrict__ Wk,
                                            const float* __restrict__ Wv,
                                            const float* __restrict__ Wo,
                                            unsigned short* __restrict__ wT,
                                            int m, int n, int tot_xg) {
  __shared__ float ts[64][65];
  __shared__ float st[4][6];
  int bid = blockIdx.x;
  int tid = threadIdx.x;
  if (bid < 256) {
    // ---- stats (byte-identical fp32 op order) + x_grid + assign ----
    if (tid < 64) {
      float mn0 = 1e30f, mx0 = -1e30f, mn1 = 1e30f, mx1 = -1e30f;
      for (int i = tid; i < SP_; i += 64) {
        float g0 = grid[i*2], g1 = grid[i*2+1];
        mn0 = fminf(mn0, g0); mx0 = fmaxf(mx0, g0);
        mn1 = fminf(mn1, g1); mx1 = fmaxf(mx1, g1);
      }
      for (int msk = 32; msk; msk >>= 1) {
        mn0 = fminf(mn0, __shfl_xor(mn0, msk));
        mx0 = fmaxf(mx0, __shfl_xor(mx0, msk));
        mn1 = fminf(mn1, __shfl_xor(mn1, msk));
        mx1 = fmaxf(mx1, __shfl_xor(mx1, msk));
      }
      if (tid == 0) {
        for (int b = 0; b < m; ++b) {
          float tmn = 1e30f, tmx = -1e30f;
          for (int tt = 0; tt < T_; ++tt) {
            float v = tg[b*T_ + tt];
            tmn = fminf(tmn, v); tmx = fmaxf(tmx, v);
          }
          st[b][0] = tmn; st[b][1] = mn0; st[b][2] = mn1;
          st[b][3] = (tmx - tmn) / (float)(T_ - 1);
          st[b][4] = (mx0 - mn0) / (float)(N0_ - 1);
          st[b][5] = (mx1 - mn1) / (float)(N1_ - 1);
        }
      }
    }
    __syncthreads();
    int idx = bid * 256 + tid;
    if (idx < tot_xg) {                       // x_grid
      int sp = idx & (SP_ - 1);
      int bt = idx >> 10;
      out[idx*3 + 0] = tg[bt];
      out[idx*3 + 1] = grid[sp*2 + 0];
      out[idx*3 + 2] = grid[sp*2 + 1];
    }
    if (idx < m*n) {                          // assign
      int b = idx / n;
      int j = idx - b*n;
      const float* s = st[b];
      float xt = x[(size_t)idx*3 + 0], x0 = x[(size_t)idx*3 + 1], x1 = x[(size_t)idx*3 + 2];
      float m0 = floorf((xt - s[0] + s[3]*0.5f) / s[3]);
      float m1 = floorf((x0 - s[1] + s[4]*0.5f) / s[4]);
      float m2 = floorf((x1 - s[2] + s[5]*0.5f) / s[5]);
      m0 = fminf(fmaxf(m0, 0.f), (float)(T_ - 1));
      m1 = fminf(fmaxf(m1, 0.f), (float)(N0_ - 1));
      m2 = fminf(fmaxf(m2, 0.f), (float)(N1_ - 1));
      int sc = (int)m0 * SP_ + (int)m1 * N1_ + (int)m2;
      int cg = b * S_ + sc;
      int old = atomicAdd(&counts[cg], 1);
      if (old < P_) cell_raw[(size_t)cg * P_ + old] = j;
    }
    return;
  }
  // ---- weight transpose+convert: wT[1024][256] = [Wq|Wk|Wv|Wo]^T ----
  int wb = bid - 256;
  int mat = wb >> 4;
  int tile = wb & 15;
  int tr = (tile >> 2) * 64;
  int tc = (tile & 3) * 64;
  const float* W = mat == 0 ? Wq : mat == 1 ? Wk : mat == 2 ? Wv : Wo;
  int r = tid >> 2, c0 = (tid & 3) * 16;
#pragma unroll
  for (int i = 0; i < 4; ++i) {
    float4 v = *(const float4*)&W[(size_t)(tr + r) * 256 + tc + c0 + i*4];
    ts[r][c0 + i*4 + 0] = v.x; ts[r][c0 + i*4 + 1] = v.y;
    ts[r][c0 + i*4 + 2] = v.z; ts[r][c0 + i*4 + 3] = v.w;
  }
  __syncthreads();
  u16x8 o0, o1;
#pragma unroll
  for (int i = 0; i < 8; ++i) o0[i] = f2bf(ts[c0 + i][r]);
#pragma unroll
  for (int i = 0; i < 8; ++i) o1[i] = f2bf(ts[c0 + 8 + i][r]);
  unsigned short* dst = wT + (size_t)(mat * 256 + tc + r) * 256 + tr + c0;
  *(u16x8*)dst = o0;
  *(u16x8*)(dst + 8) = o1;
}

// ============ fp32-A g2l GEMM body: 256 thr / 4 waves, single-buffered 48KB ================
// Tile 128x128, BK=64 (4 kt). A staged as RAW FP32 via global_load_lds (32KB, granule
// swizzle G ^= row&15), B bf16 (16KB, granule swizzle G ^= row&7). f2bf happens on the
// ds_read->fragment path. Per kt: 12 DMA/wave -> vmcnt(0) -> barrier -> compute -> barrier.
template <typename OutT>
__device__ __forceinline__ void f32a_body(char* __restrict__ ldsbuf,
                                          const float* __restrict__ A,
                                          const unsigned short* __restrict__ BT,
                                          OutT* __restrict__ C,
                                          int CP, int ldc, int L, int tid) {
  float* As = (float*)ldsbuf;                              // [128][64] fp32, row = 256B
  unsigned short* Bs = (unsigned short*)(ldsbuf + 32768);  // [128][64] bf16, row = 128B
  int rp = L / CP, cp = L - rp * CP;

  int wid = tid >> 6, lane = tid & 63, l15 = lane & 15, slot = lane >> 4;
  int wr = (wid >> 1) * 64, wc = (wid & 1) * 64;   // wave tile 64x64

  int arl = lane >> 4, aG = lane & 15;             // A-DMA: 4 rows x 16 granules
  int brl = lane >> 3, bG = lane & 7;              // B-DMA: 8 rows x 8 granules

  f32x4 acc[4][4] = {};

#pragma unroll
  for (int kt = 0; kt < 4; ++kt) {
#pragma unroll
    for (int d = 0; d < 8; ++d) {                  // A: 8 DMAs/wave (4 rows each)
      int row = wid * 32 + d * 4 + arl;
      const float* src = A + (size_t)(rp * 128 + row) * 256 + kt * 64
                         + (size_t)((aG ^ (row & 15)) << 2);
      gl_lds16(src, As + (wid * 32 + d * 4) * 64);
    }
#pragma unroll
    for (int d = 0; d < 4; ++d) {                  // B: 4 DMAs/wave (8 rows each)
      int row = wid * 32 + d * 8 + brl;
      const unsigned short* src = BT + (size_t)(cp * 128 + row) * 256 + kt * 64
                                  + (size_t)((bG ^ (row & 7)) << 3);
      gl_lds16(src, Bs + (wid * 32 + d * 8) * 64);
    }
    asm volatile("s_waitcnt vmcnt(0)" ::: "memory");
    __builtin_amdgcn_s_barrier();
    asm volatile("" ::: "memory");
#pragma unroll
    for (int kf = 0; kf < 2; ++kf) {
      short8 afr[4], bfr[4];
      int kg = kf * 4 + slot;
#pragma unroll
      for (int mm = 0; mm < 4; ++mm) {
        int row = wr + mm * 16 + l15;              // row & 15 == l15
        f32x4 a0 = *(const f32x4*)&As[row * 64 + (((2 * kg    ) ^ l15) << 2)];
        f32x4 a1 = *(const f32x4*)&As[row * 64 + (((2 * kg + 1) ^ l15) << 2)];
        short8 af;
        af[0]=f2bf(a0[0]); af[1]=f2bf(a0[1]); af[2]=f2bf(a0[2]); af[3]=f2bf(a0[3]);
        af[4]=f2bf(a1[0]); af[5]=f2bf(a1[1]); af[6]=f2bf(a1[2]); af[7]=f2bf(a1[3]);
        afr[mm] = af;
      }
#pragma unroll
      for (int nn = 0; nn < 4; ++nn) {
        int col = wc + nn * 16 + l15;              // col & 7 == l15 & 7
        bfr[nn] = *(const short8*)&Bs[col * 64 + ((kg ^ (l15 & 7)) << 3)];
      }
#pragma unroll
      for (int mm = 0; mm < 4; ++mm)
#pragma unroll
        for (int nn = 0; nn < 4; ++nn)
          acc[mm][nn] = __builtin_amdgcn_mfma_f32_16x16x32_bf16(afr[mm], bfr[nn], acc[mm][nn], 0, 0, 0);
    }
    asm volatile("" ::: "memory");
    __builtin_amdgcn_s_barrier();   // all waves done reading before next-kt overwrite
    asm volatile("" ::: "memory");
  }

  // ---- epilogue: C/D layout col=lane&15, row=(lane>>4)*4+j ----
#pragma unroll
  for (int mm = 0; mm < 4; ++mm) {
#pragma unroll
    for (int nn = 0; nn < 4; ++nn) {
      int grow0 = rp * 128 + wr + mm * 16 + slot * 4;
      int gcol  = cp * 128 + wc + nn * 16 + l15;
#pragma unroll
      for (int j = 0; j < 4; ++j) {
        size_t o = (size_t)(grow0 + j) * ldc + gcol;
        if constexpr (__is_same(OutT, float)) C[o] = acc[mm][nn][j];
        else                                  C[o] = __float2bfloat16(acc[mm][nn][j]);
      }
    }
  }
}

// ============ bf16 g2l GEMM body (Wo projection), m97 replica, single-buffered 32KB ========
template <typename OutT>
__device__ __forceinline__ void g2l_body(unsigned short* __restrict__ ldsbuf,
                                         const unsigned short* __restrict__ A,
                                         const unsigned short* __restrict__ BT,
                                         OutT* __restrict__ C,
                                         int CP, int ldc, int L, int tid) {
  int rp = L / CP, cp = L - rp * CP;

  int wid = tid >> 6, lane = tid & 63, l15 = lane & 15, slot = lane >> 4;
  int wr = (wid >> 1) * 64, wc = (wid & 1) * 64;   // wave tile 64x64

  int r8 = lane >> 3, k8 = lane & 7;
  int colsw = (k8 ^ r8) << 3;
  const unsigned short* ga0 = A  + (size_t)(rp * 128 + wid * 32 + r8) * 256 + colsw;
  const unsigned short* gb0 = BT + (size_t)(cp * 128 + wid * 32 + r8) * 256 + colsw;
  unsigned short* As = ldsbuf;
  unsigned short* Bs = ldsbuf + 8192;

  f32x4 acc[4][4] = {};

#pragma unroll
  for (int kt = 0; kt < 4; ++kt) {
    const unsigned short* ga = ga0 + kt * 64;
    const unsigned short* gb = gb0 + kt * 64;
    gl_lds16(ga,          As + (wid*32     ) * 64);
    gl_lds16(ga +  8*256, As + (wid*32 +  8) * 64);
    gl_lds16(ga + 16*256, As + (wid*32 + 16) * 64);
    gl_lds16(ga + 24*256, As + (wid*32 + 24) * 64);
    gl_lds16(gb,          Bs + (wid*32     ) * 64);
    gl_lds16(gb +  8*256, Bs + (wid*32 +  8) * 64);
    gl_lds16(gb + 16*256, Bs + (wid*32 + 16) * 64);
    gl_lds16(gb + 24*256, Bs + (wid*32 + 24) * 64);
    asm volatile("s_waitcnt vmcnt(0)" ::: "memory");
    __builtin_amdgcn_s_barrier();
    asm volatile("" ::: "memory");
#pragma unroll
    for (int kf = 0; kf < 2; ++kf) {
      short8 afr[4], bfr[4];
      int sx = (kf * 4 + slot) ^ (l15 & 7);
#pragma unroll
      for (int mm = 0; mm < 4; ++mm) {
        int row = wr + mm * 16 + l15;
        afr[mm] = *(const short8*)&As[row * 64 + (sx << 3)];
      }
#pragma unroll
      for (int nn = 0; nn < 4; ++nn) {
        int col = wc + nn * 16 + l15;
        bfr[nn] = *(const short8*)&Bs[col * 64 + (sx << 3)];
      }
#pragma unroll
      for (int mm = 0; mm < 4; ++mm)
#pragma unroll
        for (int nn = 0; nn < 4; ++nn)
          acc[mm][nn] = __builtin_amdgcn_mfma_f32_16x16x32_bf16(afr[mm], bfr[nn], acc[mm][nn], 0, 0, 0);
    }
    asm volatile("" ::: "memory");
    __builtin_amdgcn_s_barrier();
    asm volatile("" ::: "memory");
  }

#pragma unroll
  for (int mm = 0; mm < 4; ++mm) {
#pragma unroll
    for (int nn = 0; nn < 4; ++nn) {
      int grow0 = rp * 128 + wr + mm * 16 + slot * 4;
      int gcol  = cp * 128 + wc + nn * 16 + l15;
#pragma unroll
      for (int j = 0; j < 4; ++j) {
        size_t o = (size_t)(grow0 + j) * ldc + gcol;
        if constexpr (__is_same(OutT, float)) C[o] = acc[mm][nn][j];
        else                                  C[o] = __float2bfloat16(acc[mm][nn][j]);
      }
    }
  }
}

// ============ phase2: [0..2048) kv GEMM | [2048..2096) lat GEMM | [2096..2224) finalize ====
__global__ __launch_bounds__(256, 3) void phase2(const float* __restrict__ z,
                                                 const unsigned short* __restrict__ wT,
                                                 __hip_bfloat16* __restrict__ kv,
                                                 const float* __restrict__ latents,
                                                 float* __restrict__ lat,
                                                 const int* __restrict__ counts,
                                                 int* __restrict__ cell_raw,
                                                 int* __restrict__ pts2, int total) {
  __shared__ char lds[49152];   // 48KB: A fp32 32KB + B bf16 16KB, shared by both paths
  int bid = blockIdx.x;
  if (bid < 2048) {
    int L = (bid & 7) * 256 + (bid >> 3);     // XCD-chunked over the kv range
    f32a_body<__hip_bfloat16>(lds, z, wT + (size_t)256*256, kv, 4, 512, L, threadIdx.x);
    return;
  }
  if (bid < 2096) {
    f32a_body<float>(lds, latents, wT, lat, 6, 768, bid - 2048, threadIdx.x);
    return;
  }
  int cg = (bid - 2096) * 256 + threadIdx.x;
  if (cg >= total) return;
  int cnt = counts[cg];
  int stored = cnt < P_ ? cnt : P_;
  int eff = cnt < (P_ - 1) ? cnt : (P_ - 1);
  int* p = cell_raw + (size_t)cg * P_;
  for (int i = 1; i < stored; ++i) {   // insertion sort ascending (original index order)
    int key = p[i]; int j = i - 1;
    while (j >= 0 && p[j] > key) { p[j+1] = p[j]; --j; }
    p[j+1] = key;
  }
  int* o = pts2 + (size_t)cg * P_;
  o[0] = eff;
  for (int i = 0; i < eff; ++i) o[1 + i] = p[i];
}

// ============ standalone bf16 g2l GEMM (Wo projection) =====================================
template <typename OutT>
__global__ __launch_bounds__(256, 3) void gemm_g2l(const unsigned short* __restrict__ A,
                                                   const unsigned short* __restrict__ BT,
                                                   OutT* __restrict__ C,
                                                   int CP, int ldc) {
  __shared__ unsigned short lds[2 * 128 * 64];
  int nb = gridDim.x, bid = blockIdx.x;
  int L = bid;
  if ((nb & 7) == 0) L = (bid & 7) * (nb >> 3) + (bid >> 3);
  g2l_body<OutT>(lds, A, BT, C, CP, ldc, L, threadIdx.x);
}

// ---------------- masked cross-attention: one wave per cell, parallel softmax -------------
// Logits are bounded (|p| << 88) so no max-subtraction: every point update is independent.
__global__ __launch_bounds__(256) void attn_kernel(
    const float* __restrict__ lat,          // [1024][768]  q|k|v
    const __hip_bfloat16* __restrict__ kv,  // [m*n][512]   k|v
    const int* __restrict__ pts2,           // [MS][16]: w0=eff, w1..15 sorted pt indices
    __hip_bfloat16* __restrict__ attn_out, int n) {
  const float scale = 0.17677669529663687f;  // 1/sqrt(32)
  int wid = threadIdx.x >> 6;
  int lane = threadIdx.x & 63;
  int cellg = blockIdx.x * 4 + wid;
  int b = cellg >> 13;                 // S_=8192, cells per batch
  int c = cellg & (SP_ - 1);           // spatial index -> latent row
  int d0 = lane << 2;                  // 4 dims per lane

  const int* pp = pts2 + (size_t)cellg * P_;
  int4 h0 = *(const int4*)pp;          // eff, pt0, pt1, pt2 (broadcast load)
  int eff = h0.x;

  const float* latc = lat + c * 768 + d0;
  float4 q  = *(const float4*)latc;
  float4 kl = *(const float4*)(latc + 256);
  float4 vl = *(const float4*)(latc + 512);

  // grid-token term
  float p15 = q.x*kl.x + q.y*kl.y + q.z*kl.z + q.w*kl.w;
  p15 += __shfl_xor(p15, 1);
  p15 += __shfl_xor(p15, 2);
  p15 += __shfl_xor(p15, 4);           // head-local (8 lanes = 32 dims)
  float e15 = __expf(p15 * scale);
  float ssum = e15;
  float4 acc;
  acc.x = e15 * vl.x; acc.y = e15 * vl.y; acc.z = e15 * vl.z; acc.w = e15 * vl.w;

  const unsigned short* kvp = (const unsigned short*)kv;
  size_t bbase = (size_t)b * n;

  int pt[4]; pt[0] = h0.y; pt[1] = h0.z; pt[2] = h0.w; pt[3] = 0;
  int done = 0, cap = 3;
  while (done < eff) {
    int np = eff - done; if (np > cap) np = cap;
    ushort4 kr[4], vr[4];
#pragma unroll
    for (int i = 0; i < 4; ++i) if (i < np) {
      size_t row = (bbase + (size_t)pt[i]) * 512;
      kr[i] = *(const ushort4*)(kvp + row + d0);
      vr[i] = *(const ushort4*)(kvp + row + 256 + d0);
    }
    float e[4];
#pragma unroll
    for (int i = 0; i < 4; ++i) if (i < np) {
      float p = q.x*bf2f(kr[i].x) + q.y*bf2f(kr[i].y) + q.z*bf2f(kr[i].z) + q.w*bf2f(kr[i].w);
      p += __shfl_xor(p, 1);
      p += __shfl_xor(p, 2);
      p += __shfl_xor(p, 4);
      e[i] = __expf(p * scale);
    }
#pragma unroll
    for (int i = 0; i < 4; ++i) if (i < np) {
      ssum += e[i];
      acc.x += e[i] * bf2f(vr[i].x);
      acc.y += e[i] * bf2f(vr[i].y);
      acc.z += e[i] * bf2f(vr[i].z);
      acc.w += e[i] * bf2f(vr[i].w);
    }
    done += np;
    cap = 4;
    if (done < eff) {
      int4 h = *(const int4*)(pp + 1 + done);   // done in {3,7,11} -> aligned
      pt[0] = h.x; pt[1] = h.y; pt[2] = h.z; pt[3] = h.w;
    }
  }
  float inv = 1.f / ssum;
  ushort4 o;
  o.x = f2bf(acc.x * inv); o.y = f2bf(acc.y * inv);
  o.z = f2bf(acc.z * inv); o.w = f2bf(acc.w * inv);
  *(ushort4*)((unsigned short*)attn_out + (size_t)cellg * E_ + d0) = o;
}

// -------------------------------------------------------------------------------------------
extern "C" void kernel_launch(void* const* d_in, const int* in_sizes, int n_in,
                              void* d_out, int out_size, void* d_ws, size_t ws_size,
                              hipStream_t stream) {
  const float* x       = (const float*)d_in[0];
  const float* z       = (const float*)d_in[1];
  const float* tg      = (const float*)d_in[2];
  const float* latents = (const float*)d_in[3];
  const float* grid    = (const float*)d_in[4];
  const float* Wq      = (const float*)d_in[5];
  const float* Wk      = (const float*)d_in[6];
  const float* Wv      = (const float*)d_in[7];
  const float* Wo      = (const float*)d_in[8];

  int m = in_sizes[2] / T_;              // 4
  int n = in_sizes[1] / (m * E_);        // 16384
  int MS = m * S_;                       // 32768
  float* out = (float*)d_out;
  int tot_xg = m * T_ * SP_;             // 32768 grid sites

  // ---- workspace carve (256B aligned) ----
  char* w = (char*)d_ws;
  auto alloc = [&](size_t bytes) { char* p = w; w += (bytes + 255) & ~(size_t)255; return p; };
  int*   counts     = (int*)  alloc((size_t)MS * 4);
  int*   cell_raw   = (int*)  alloc((size_t)MS * P_ * 4);
  int*   pts2       = (int*)  alloc((size_t)MS * P_ * 4);
  unsigned short* wT = (unsigned short*)alloc((size_t)1024 * 256 * 2);
  float* lat        = (float*)alloc((size_t)SP_ * 768 * 4);
  __hip_bfloat16* kv       = (__hip_bfloat16*)alloc((size_t)m * n * 512 * 2);
  __hip_bfloat16* attn_out = (__hip_bfloat16*)alloc((size_t)MS * E_ * 2);

  // 0) zero the atomic counters
  (void)hipMemsetAsync(counts, 0, (size_t)MS * 4, stream);

  // 1) prep: stats+x_grid+assign | wtrans   (320 blocks)
  prep<<<320, 256, 0, stream>>>(x, tg, grid, out, counts, cell_raw,
                                Wq, Wk, Wv, Wo, wT, m, n, tot_xg);

  // 2) phase2: kv GEMM fp32-A (2048) | lat GEMM fp32-A (48) | finalize (128)
  phase2<<<2224, 256, 0, stream>>>(z, wT, kv, latents, lat, counts, cell_raw, pts2, MS);

  // 3) attention: one wave per cell (parallel softmax)
  attn_kernel<<<MS/4, 256, 0, stream>>>(lat, kv, pts2, attn_out, n);

  // 4) output projection -> z_grid   (256 rp x 2 cp)
  gemm_g2l<float><<<512, 256, 0, stream>>>(
      (const unsigned short*)attn_out, wT + (size_t)768*256, out + (size_t)tot_xg * 3, 2, 256);
}